// Round 8
// baseline (10744.001 us; speedup 1.0000x reference)
//
#include <hip/hip_runtime.h>
#include <math.h>

typedef unsigned short u16;
typedef unsigned int   u32;
typedef unsigned long long u64;
typedef __bf16 bf16x8 __attribute__((ext_vector_type(8)));
typedef float  f32x4  __attribute__((ext_vector_type(4)));

#define BB 256
#define TT 256
#define HD 256
#define ED 128
#define DEPTH 4

/* ws layout (u32 units):
   [0, H_U32)        : h ring, packed bf16 hi|lo<<16  [10][DEPTH][256][256]
   [H_U32, +FLG_U32) : flags [10][256][2] padded x4 (16B)
   [XP_OFF, +XP_U32) : packed x  [256][256][8]
   [WT_OFF, ...)     : fragment-ordered bf16 weights (r4-r7 proven layout)  */
#define H_U32   (10 * DEPTH * BB * HD)
#define FLG_U32 (10 * TT * 2 * 4)
#define XP_OFF  (H_U32 + FLG_U32)
#define XP_U32  (BB * TT * 8)
#define WT_OFF  (XP_OFF + XP_U32)

__constant__ size_t g_woff[10] = {0ul,589824ul,1638400ul,2686976ul,3735552ul,
                                  4784128ul,5177344ul,5439488ul,5701632ul,5963776ul};
__constant__ int g_cb[11] = {0,73728,204800,335872,466944,598016,
                             647168,679936,712704,745472,778240};

__device__ __forceinline__ u16 f2bf_hi(float f) {
    u32 u = __float_as_uint(f);
    u32 r = (u + 0x7FFFu + ((u >> 16) & 1u)) >> 16;
    return (u16)r;
}
__device__ __forceinline__ float bf2f(u16 h) { return __uint_as_float(((u32)h) << 16); }
__device__ __forceinline__ float sigmoidf_(float v) { return 1.0f / (1.0f + expf(-v)); }

__global__ __launch_bounds__(256) void zero_state(u32* wsd) {
    const int n = H_U32 + FLG_U32;
    for (int i = blockIdx.x * blockDim.x + threadIdx.x; i < n; i += gridDim.x * blockDim.x)
        wsd[i] = 0u;
}

__global__ __launch_bounds__(256) void conv_x(const float* __restrict__ x, u32* __restrict__ wsd) {
    u32* xp = wsd + XP_OFF;
    for (int i = blockIdx.x * blockDim.x + threadIdx.x; i < XP_U32; i += gridDim.x * blockDim.x) {
        float v = x[i];
        u16 hi = f2bf_hi(v);
        u16 lo = f2bf_hi(v - bf2f(hi));
        xp[i] = (u32)hi | ((u32)lo << 16);
    }
}

/* weights -> bf16 hi/lo, MFMA fragment order (identical to rounds 4-7) */
__global__ __launch_bounds__(256) void conv_all(
    const float* __restrict__ w_ih0_1, const float* __restrict__ w_ihr_1,
    const float* __restrict__ w_hh_1,
    const float* __restrict__ w_ih0_2, const float* __restrict__ w_ihr_2,
    const float* __restrict__ w_hh_2,
    u32* __restrict__ wsd)
{
    __bf16* dst0 = (__bf16*)(wsd + WT_OFF);
    const int nch = 778240;
    for (int ci = blockIdx.x * blockDim.x + threadIdx.x; ci < nch;
         ci += gridDim.x * blockDim.x) {
        int l = 0;
        while (ci >= g_cb[l + 1]) ++l;
        int di = ci - g_cb[l];

        const int hd  = (l < 5) ? 256 : 128;
        const int din = (l == 0) ? 32 : ((l < 6) ? 256 : 128);
        const int xw  = (l == 0) ? 8 : din;
        const int Kp  = din + hd;
        const int nk  = Kp >> 5;

        const float *wih, *whh; int wihld, whhld;
        if (l == 0)      { wih = w_ih0_1;                                whh = w_hh_1;
                           wihld = 8;   whhld = 256; }
        else if (l < 5)  { wih = w_ihr_1 + (size_t)(l - 1) * 1024 * 256; whh = w_hh_1 + (size_t)l * 1024 * 256;
                           wihld = 256; whhld = 256; }
        else if (l == 5) { wih = w_ih0_2;                                whh = w_hh_2;
                           wihld = 256; whhld = 128; }
        else             { wih = w_ihr_2 + (size_t)(l - 6) * 512 * 128;  whh = w_hh_2 + (size_t)(l - 5) * 512 * 128;
                           wihld = 128; whhld = 128; }

        int lane = di & 63;
        int rem  = di >> 6;
        int kt   = rem % nk;
        int rem2 = rem / nk;
        int p    = rem2 & 1;
        int g    = (rem2 >> 1) & 3;
        int jt   = rem2 >> 3;
        int r15  = lane & 15, kq = lane >> 4;
        int row  = g * hd + jt * 16 + r15;

        bf16x8 o8;
        #pragma unroll
        for (int e = 0; e < 8; ++e) {
            int k = kt * 32 + kq * 8 + e;
            float v = 0.0f;
            if (k < xw) v = wih[(size_t)row * wihld + k];
            else if (k >= din && k < Kp) v = whh[(size_t)row * whhld + (k - din)];
            __bf16 h = (__bf16)v;
            o8[e] = p ? (__bf16)(v - (float)h) : h;
        }
        *(bf16x8*)(dst0 + g_woff[l] + (size_t)di * 8) = o8;
    }
}

struct U64x8 { u64 q[8]; };

__device__ __forceinline__ void unpack4(const u64* q, bf16x8& bh, bf16x8& bl) {
    union { u64 q2[4]; u32 w[8]; } U;
    U.q2[0] = q[0]; U.q2[1] = q[1]; U.q2[2] = q[2]; U.q2[3] = q[3];
    union { u32 u[4]; bf16x8 v; } H, L;
    #pragma unroll
    for (int i = 0; i < 4; ++i) {
        u32 a = U.w[2 * i], b = U.w[2 * i + 1];
        H.u[i] = (a & 0xFFFFu) | (b << 16);
        L.u[i] = (a >> 16) | (b & 0xFFFF0000u);
    }
    bh = H.v; bl = L.v;
}

__device__ __forceinline__ int fidx(int l_, int t_, int bt_) {
    return ((l_ * TT + t_) * 2 + bt_) * 4;
}

/* wave-cooperative wait on up to 2 flags (lanes 0/1 poll, __any spins) */
__device__ __forceinline__ void waitflags(const u32* f0, u32 t0, const u32* f1, u32 t1) {
    const int lane = threadIdx.x & 63;
    const u32* p = (lane == 0) ? f0 : ((lane == 1) ? f1 : nullptr);
    const u32 tg = (lane == 0) ? t0 : t1;
    bool pend = (p != nullptr);
    for (int it = 0; it < (1 << 18); ++it) {
        if (pend && __hip_atomic_load(p, __ATOMIC_RELAXED, __HIP_MEMORY_SCOPE_AGENT) >= tg)
            pend = false;
        if (!__any(pend)) return;
        __builtin_amdgcn_s_sleep(1);
    }
}

/* one K-half GEMM: B via caller lambda (4-deep ring), A-hi from LDS,
   A-lo streamed from global/L2 (2-deep). 24 MFMA per kt (4g x 2tiles x 3). */
template<int N, typename LB>
__device__ __forceinline__ void gemm_half(const LB& ldB, int ktBase,
    const u16* __restrict__ A_hi, const u16* __restrict__ wlo0, size_t gs,
    int nk512, int lane8, f32x4 (&acc)[4][2])
{
    U64x8 b[4];
    uint4 alo[2][4];
    #pragma unroll
    for (int i = 0; i < 4; ++i) if (i < N) ldB(ktBase + i, b[i]);
    #pragma unroll
    for (int i = 0; i < 2; ++i) if (i < N) {
        #pragma unroll
        for (int g = 0; g < 4; ++g)
            alo[i][g] = *(const uint4*)(wlo0 + (size_t)g * gs + (size_t)(ktBase + i) * 512);
    }
    #pragma unroll
    for (int kt = 0; kt < N; ++kt) {
        U64x8 cb;
        #pragma unroll
        for (int i = 0; i < 8; ++i) cb.q[i] = b[kt & 3].q[i];
        if (kt + 4 < N) ldB(ktBase + kt + 4, b[kt & 3]);
        uint4 ca[4];
        #pragma unroll
        for (int g = 0; g < 4; ++g) ca[g] = alo[kt & 1][g];
        if (kt + 2 < N) {
            #pragma unroll
            for (int g = 0; g < 4; ++g)
                alo[kt & 1][g] = *(const uint4*)(wlo0 + (size_t)g * gs + (size_t)(ktBase + kt + 2) * 512);
        }
        bf16x8 bh0, bl0, bh1, bl1;
        unpack4(&cb.q[0], bh0, bl0);
        unpack4(&cb.q[4], bh1, bl1);
        const int kof = (ktBase + kt) * 512 + lane8;
        #pragma unroll
        for (int g = 0; g < 4; ++g) {
            bf16x8 ah = *(const bf16x8*)&A_hi[g * nk512 + kof];
            union { uint4 u; bf16x8 v; } AL; AL.u = ca[g];
            bf16x8 al = AL.v;
            acc[g][0] = __builtin_amdgcn_mfma_f32_16x16x32_bf16(ah, bh0, acc[g][0], 0,0,0);
            acc[g][1] = __builtin_amdgcn_mfma_f32_16x16x32_bf16(ah, bh1, acc[g][1], 0,0,0);
            acc[g][0] = __builtin_amdgcn_mfma_f32_16x16x32_bf16(ah, bl0, acc[g][0], 0,0,0);
            acc[g][1] = __builtin_amdgcn_mfma_f32_16x16x32_bf16(ah, bl1, acc[g][1], 0,0,0);
            acc[g][0] = __builtin_amdgcn_mfma_f32_16x16x32_bf16(al, bh0, acc[g][0], 0,0,0);
            acc[g][1] = __builtin_amdgcn_mfma_f32_16x16x32_bf16(al, bh1, acc[g][1], 0,0,0);
        }
    }
}

template<int NKI, int NKR, bool ISL0>
__device__ void run_all(int l, int jt, int bt,
    const u32* __restrict__ xp, const float* __restrict__ bias,
    u32* __restrict__ hbuf, u32* __restrict__ flg, float* __restrict__ out,
    const u16* __restrict__ A_hi, f32x4* __restrict__ XCH, const u16* __restrict__ wt)
{
    constexpr int NK = NKI + NKR;
    const int tid  = threadIdx.x;
    const int lane = tid & 63;
    const int wv   = tid >> 6;
    const bool isA = (wv < 4);          /* input-half waves */
    const int wp   = wv & 3;            /* pair index: A-wp <-> B-wp share batches */
    const int r15  = lane & 15;
    const int kq   = lane >> 4;
    const int brow0 = bt * 128 + wp * 32 + r15;
    const int j0   = jt * 16 + kq * 4;
    const int lane8 = lane * 8;
    const int nk512 = NK * 512;
    const size_t gs = (size_t)2 * NK * 512;
    const u16* wlo0 = wt + g_woff[l] + (size_t)(jt * 8 + 1) * NK * 512 + lane8;

    const u32 tMY = ((l < 5) ? 16u : 8u) * 4u;
    const u32 tLO = (((l - 1) < 5) ? 16u : 8u) * 4u;
    const u32 tDN = (((l + 1) < 5) ? 16u : 8u) * 4u;
    const int hd  = (l < 5) ? 256 : 128;

    float bias_r[4][4];
    float4 cv0 = make_float4(0.f,0.f,0.f,0.f), cv1 = make_float4(0.f,0.f,0.f,0.f);
    if (!isA) {
        #pragma unroll
        for (int g = 0; g < 4; ++g) {
            float4 v = *(const float4*)&bias[g * hd + j0];
            bias_r[g][0] = v.x; bias_r[g][1] = v.y; bias_r[g][2] = v.z; bias_r[g][3] = v.w;
        }
    }

    for (int t = 0; t < TT; ++t) {
        const u32* hin   = hbuf + ((size_t)(ISL0 ? 0 : (l - 1)) * DEPTH + (t & 3)) * (BB * HD);
        const u32* hprev = hbuf + ((size_t)l * DEPTH + ((t - 1) & 3)) * (BB * HD);
        u32*       hout  = hbuf + ((size_t)l * DEPTH + (t & 3)) * (BB * HD);

        f32x4 acc[4][2];
        #pragma unroll
        for (int g = 0; g < 4; ++g) {
            acc[g][0] = (f32x4){0.f,0.f,0.f,0.f};
            acc[g][1] = (f32x4){0.f,0.f,0.f,0.f};
        }

        if (isA) {
            if (!ISL0) waitflags(flg + fidx(l - 1, t, bt), tLO, nullptr, 0u);
            auto ldB = [&](int kt, U64x8& v) {
                if constexpr (ISL0) {
                    if (kq == 0) {
                        const u64* p0 = (const u64*)(xp + ((size_t)brow0 * TT + t) * 8);
                        const u64* p1 = (const u64*)(xp + ((size_t)(brow0 + 16) * TT + t) * 8);
                        #pragma unroll
                        for (int i = 0; i < 4; ++i) { v.q[i] = p0[i]; v.q[4 + i] = p1[i]; }
                    } else {
                        #pragma unroll
                        for (int i = 0; i < 8; ++i) v.q[i] = 0ull;
                    }
                } else {
                    const int k0 = kt * 32 + kq * 8;
                    const u64* p0 = (const u64*)(hin + (size_t)brow0 * HD + k0);
                    const u64* p1 = (const u64*)(hin + (size_t)(brow0 + 16) * HD + k0);
                    #pragma unroll
                    for (int i = 0; i < 4; ++i) {
                        v.q[i]   = __hip_atomic_load(p0 + i, __ATOMIC_RELAXED, __HIP_MEMORY_SCOPE_AGENT);
                        v.q[4+i] = __hip_atomic_load(p1 + i, __ATOMIC_RELAXED, __HIP_MEMORY_SCOPE_AGENT);
                    }
                }
            };
            gemm_half<NKI>(ldB, 0, A_hi, wlo0, gs, nk512, lane8, acc);
            /* publish partials (swizzled: slot (r+lane)&7 -> conflict-spread) */
            f32x4* X = XCH + (((size_t)(t & 1) * 4 + wp) * 64 + lane) * 8;
            #pragma unroll
            for (int g = 0; g < 4; ++g)
                #pragma unroll
                for (int ti = 0; ti < 2; ++ti)
                    X[((g * 2 + ti) + lane) & 7] = acc[g][ti];
        } else {
            waitflags(t > 0 ? flg + fidx(l, t - 1, bt) : nullptr, tMY,
                      (l < 9 && t >= DEPTH) ? flg + fidx(l + 1, t - DEPTH, bt) : nullptr, tDN);
            auto ldB = [&](int kt, U64x8& v) {
                const int k0 = (kt - NKI) * 32 + kq * 8;
                const u64* p0 = (const u64*)(hprev + (size_t)brow0 * HD + k0);
                const u64* p1 = (const u64*)(hprev + (size_t)(brow0 + 16) * HD + k0);
                #pragma unroll
                for (int i = 0; i < 4; ++i) {
                    v.q[i]   = __hip_atomic_load(p0 + i, __ATOMIC_RELAXED, __HIP_MEMORY_SCOPE_AGENT);
                    v.q[4+i] = __hip_atomic_load(p1 + i, __ATOMIC_RELAXED, __HIP_MEMORY_SCOPE_AGENT);
                }
            };
            gemm_half<NKR>(ldB, NKI, A_hi, wlo0, gs, nk512, lane8, acc);
        }

        __syncthreads();   /* A-partials visible; XCH dbuf keeps A free to run ahead */

        if (!isA) {
            const f32x4* X = XCH + (((size_t)(t & 1) * 4 + wp) * 64 + lane) * 8;
            #pragma unroll
            for (int g = 0; g < 4; ++g)
                #pragma unroll
                for (int ti = 0; ti < 2; ++ti)
                    acc[g][ti] += X[((g * 2 + ti) + lane) & 7];

            #pragma unroll
            for (int ti = 0; ti < 2; ++ti) {
                float4& cv = ti ? cv1 : cv0;
                const int brow = brow0 + ti * 16;
                float4 hv;
                {
                    float i_, f_, g_, o_;
                    i_ = sigmoidf_(acc[0][ti][0] + bias_r[0][0]); f_ = sigmoidf_(acc[1][ti][0] + bias_r[1][0]);
                    g_ = tanhf   (acc[2][ti][0] + bias_r[2][0]); o_ = sigmoidf_(acc[3][ti][0] + bias_r[3][0]);
                    cv.x = fmaf(f_, cv.x, i_ * g_); hv.x = o_ * tanhf(cv.x);
                    i_ = sigmoidf_(acc[0][ti][1] + bias_r[0][1]); f_ = sigmoidf_(acc[1][ti][1] + bias_r[1][1]);
                    g_ = tanhf   (acc[2][ti][1] + bias_r[2][1]); o_ = sigmoidf_(acc[3][ti][1] + bias_r[3][1]);
                    cv.y = fmaf(f_, cv.y, i_ * g_); hv.y = o_ * tanhf(cv.y);
                    i_ = sigmoidf_(acc[0][ti][2] + bias_r[0][2]); f_ = sigmoidf_(acc[1][ti][2] + bias_r[1][2]);
                    g_ = tanhf   (acc[2][ti][2] + bias_r[2][2]); o_ = sigmoidf_(acc[3][ti][2] + bias_r[3][2]);
                    cv.z = fmaf(f_, cv.z, i_ * g_); hv.z = o_ * tanhf(cv.z);
                    i_ = sigmoidf_(acc[0][ti][3] + bias_r[0][3]); f_ = sigmoidf_(acc[1][ti][3] + bias_r[1][3]);
                    g_ = tanhf   (acc[2][ti][3] + bias_r[2][3]); o_ = sigmoidf_(acc[3][ti][3] + bias_r[3][3]);
                    cv.w = fmaf(f_, cv.w, i_ * g_); hv.w = o_ * tanhf(cv.w);
                }
                u32 pk0, pk1, pk2, pk3;
                {
                    u16 h0 = f2bf_hi(hv.x); pk0 = (u32)h0 | ((u32)f2bf_hi(hv.x - bf2f(h0)) << 16);
                    u16 h1 = f2bf_hi(hv.y); pk1 = (u32)h1 | ((u32)f2bf_hi(hv.y - bf2f(h1)) << 16);
                    u16 h2 = f2bf_hi(hv.z); pk2 = (u32)h2 | ((u32)f2bf_hi(hv.z - bf2f(h2)) << 16);
                    u16 h3 = f2bf_hi(hv.w); pk3 = (u32)h3 | ((u32)f2bf_hi(hv.w - bf2f(h3)) << 16);
                }
                u64* hp = (u64*)(hout + (size_t)brow * HD + j0);
                __hip_atomic_store(hp + 0, (u64)pk0 | ((u64)pk1 << 32), __ATOMIC_RELAXED, __HIP_MEMORY_SCOPE_AGENT);
                __hip_atomic_store(hp + 1, (u64)pk2 | ((u64)pk3 << 32), __ATOMIC_RELAXED, __HIP_MEMORY_SCOPE_AGENT);
                if (l == 9 && t == TT - 1)
                    *(float4*)&out[(size_t)brow * ED + j0] = hv;
            }
            /* drain this wave's stores, then its flag contribution */
            __builtin_amdgcn_s_waitcnt(0);
            if (lane == 0)
                __hip_atomic_fetch_add(flg + fidx(l, t, bt), 1u,
                                       __ATOMIC_RELAXED, __HIP_MEMORY_SCOPE_AGENT);
        }
    }
}

/* 256 blocks, 512 thr. XCD-clustered mapping (bid%8 = XCD):
   xcd 0-3 -> layers 1-4 (32 blk), xcd4 -> layer0, xcd5 -> l5+l6,
   xcd6 -> l7+l8, xcd7 -> l9 (+16 idle). */
__global__ __launch_bounds__(512) void lstm_persist(
    const float* __restrict__ b_1, const float* __restrict__ b_2,
    u32* __restrict__ wsd, float* __restrict__ out)
{
    __shared__ __align__(16) u16  A_hi_sh[4 * 16 * 512];   /* 64 KiB */
    __shared__ __align__(16) f32x4 XCH_sh[2 * 4 * 64 * 8]; /* 64 KiB */

    const int bid = blockIdx.x;
    const int xcd = bid & 7, slot = bid >> 3;
    int l, jt, bt;
    if (xcd < 5)      { l = (xcd == 4) ? 0 : (xcd + 1); jt = slot >> 1; bt = slot & 1; }
    else if (xcd == 5){ l = (slot < 16) ? 5 : 6; int s2 = slot & 15; jt = s2 >> 1; bt = s2 & 1; }
    else if (xcd == 6){ l = (slot < 16) ? 7 : 8; int s2 = slot & 15; jt = s2 >> 1; bt = s2 & 1; }
    else              { if (slot >= 16) return; l = 9; jt = slot >> 1; bt = slot & 1; }

    const int hd  = (l < 5) ? 256 : 128;
    const int din = (l == 0) ? 32 : ((l < 6) ? 256 : 128);
    const int nk  = (din + hd) >> 5;
    const float* bias = (l < 5) ? (b_1 + l * 1024) : (b_2 + (l - 5) * 512);

    u32* hbuf = wsd;
    u32* flg  = wsd + H_U32;
    const u32* xp = wsd + XP_OFF;
    const u16* wt = (const u16*)(wsd + WT_OFF);

    /* one-time: hi-half weight fragments -> LDS (4 gate runs, p=0) */
    {
        const int n4 = nk * 64;  /* uint4 per gate run */
        for (int g = 0; g < 4; ++g) {
            const uint4* s = (const uint4*)(wt + g_woff[l] + (size_t)((jt * 4 + g) * 2) * nk * 512);
            uint4* d = (uint4*)(A_hi_sh + g * nk * 512);
            for (int i = threadIdx.x; i < n4; i += 512) d[i] = s[i];
        }
    }
    __syncthreads();

    if (l == 0)
        run_all<1, 8, true >(l, jt, bt, xp, bias, hbuf, flg, out, A_hi_sh, XCH_sh, wt);
    else if (l < 5)
        run_all<8, 8, false>(l, jt, bt, xp, bias, hbuf, flg, out, A_hi_sh, XCH_sh, wt);
    else if (l == 5)
        run_all<8, 4, false>(l, jt, bt, xp, bias, hbuf, flg, out, A_hi_sh, XCH_sh, wt);
    else
        run_all<4, 4, false>(l, jt, bt, xp, bias, hbuf, flg, out, A_hi_sh, XCH_sh, wt);
}

extern "C" void kernel_launch(void* const* d_in, const int* in_sizes, int n_in,
                              void* d_out, int out_size, void* d_ws, size_t ws_size,
                              hipStream_t stream) {
    const float* x       = (const float*)d_in[0];
    const float* w_ih0_1 = (const float*)d_in[1];
    const float* w_ihr_1 = (const float*)d_in[2];
    const float* w_hh_1  = (const float*)d_in[3];
    const float* b_1     = (const float*)d_in[4];
    const float* w_ih0_2 = (const float*)d_in[5];
    const float* w_ihr_2 = (const float*)d_in[6];
    const float* w_hh_2  = (const float*)d_in[7];
    const float* b_2     = (const float*)d_in[8];
    u32*   wsd = (u32*)d_ws;
    float* out = (float*)d_out;

    hipLaunchKernelGGL(zero_state, dim3(1024), dim3(256), 0, stream, wsd);
    hipLaunchKernelGGL(conv_all, dim3(1024), dim3(256), 0, stream,
                       w_ih0_1, w_ihr_1, w_hh_1, w_ih0_2, w_ihr_2, w_hh_2, wsd);
    hipLaunchKernelGGL(conv_x, dim3(256), dim3(256), 0, stream, x, wsd);
    hipLaunchKernelGGL(lstm_persist, dim3(256), dim3(512), 0, stream,
                       b_1, b_2, wsd, out);
}

// Round 9
// 3373.725 us; speedup vs baseline: 3.1846x; 3.1846x over previous
//
#include <hip/hip_runtime.h>
#include <math.h>

typedef unsigned short u16;
typedef unsigned int   u32;
typedef unsigned long long u64;
typedef __bf16 bf16x8 __attribute__((ext_vector_type(8)));
typedef float  f32x4  __attribute__((ext_vector_type(4)));

#define BB 256
#define TT 256
#define HD 256
#define ED 128
#define NSTEPS 265

/* ws layout (u32 units):
   [0, H_U32)        : h ping-pong, packed bf16 hi|lo<<16  [10][2][256][256]
   [CTR_OFF, +256)   : 8 barrier counters, 128B padded
   [XP_OFF, +XP_U32) : packed x  [256][256][8]
   [WT_OFF, ...)     : fragment-ordered bf16 weights (r4-r8 proven layout) */
#define H_U32   (10 * 2 * BB * HD)
#define CTR_OFF H_U32
#define CTR_U32 256
#define XP_OFF  (H_U32 + CTR_U32)
#define XP_U32  (BB * TT * 8)
#define WT_OFF  (XP_OFF + XP_U32)

__constant__ size_t g_woff[10] = {0ul,589824ul,1638400ul,2686976ul,3735552ul,
                                  4784128ul,5177344ul,5439488ul,5701632ul,5963776ul};
__constant__ int g_cb[11] = {0,73728,204800,335872,466944,598016,
                             647168,679936,712704,745472,778240};

__device__ __forceinline__ u16 f2bf_hi(float f) {
    u32 u = __float_as_uint(f);
    u32 r = (u + 0x7FFFu + ((u >> 16) & 1u)) >> 16;
    return (u16)r;
}
__device__ __forceinline__ float bf2f(u16 h) { return __uint_as_float(((u32)h) << 16); }
__device__ __forceinline__ float sigmoidf_(float v) { return 1.0f / (1.0f + expf(-v)); }

__global__ __launch_bounds__(256) void zero_state(u32* wsd) {
    const int n = XP_OFF;
    for (int i = blockIdx.x * blockDim.x + threadIdx.x; i < n; i += gridDim.x * blockDim.x)
        wsd[i] = 0u;
}

__global__ __launch_bounds__(256) void conv_x(const float* __restrict__ x, u32* __restrict__ wsd) {
    u32* xp = wsd + XP_OFF;
    for (int i = blockIdx.x * blockDim.x + threadIdx.x; i < XP_U32; i += gridDim.x * blockDim.x) {
        float v = x[i];
        u16 hi = f2bf_hi(v);
        u16 lo = f2bf_hi(v - bf2f(hi));
        xp[i] = (u32)hi | ((u32)lo << 16);
    }
}

/* weights -> bf16 hi/lo, MFMA fragment order (identical to rounds 4-8) */
__global__ __launch_bounds__(256) void conv_all(
    const float* __restrict__ w_ih0_1, const float* __restrict__ w_ihr_1,
    const float* __restrict__ w_hh_1,
    const float* __restrict__ w_ih0_2, const float* __restrict__ w_ihr_2,
    const float* __restrict__ w_hh_2,
    u32* __restrict__ wsd)
{
    __bf16* dst0 = (__bf16*)(wsd + WT_OFF);
    const int nch = 778240;
    for (int ci = blockIdx.x * blockDim.x + threadIdx.x; ci < nch;
         ci += gridDim.x * blockDim.x) {
        int l = 0;
        while (ci >= g_cb[l + 1]) ++l;
        int di = ci - g_cb[l];

        const int hd  = (l < 5) ? 256 : 128;
        const int din = (l == 0) ? 32 : ((l < 6) ? 256 : 128);
        const int xw  = (l == 0) ? 8 : din;
        const int Kp  = din + hd;
        const int nk  = Kp >> 5;

        const float *wih, *whh; int wihld, whhld;
        if (l == 0)      { wih = w_ih0_1;                                whh = w_hh_1;
                           wihld = 8;   whhld = 256; }
        else if (l < 5)  { wih = w_ihr_1 + (size_t)(l - 1) * 1024 * 256; whh = w_hh_1 + (size_t)l * 1024 * 256;
                           wihld = 256; whhld = 256; }
        else if (l == 5) { wih = w_ih0_2;                                whh = w_hh_2;
                           wihld = 256; whhld = 128; }
        else             { wih = w_ihr_2 + (size_t)(l - 6) * 512 * 128;  whh = w_hh_2 + (size_t)(l - 5) * 512 * 128;
                           wihld = 128; whhld = 128; }

        int lane = di & 63;
        int rem  = di >> 6;
        int kt   = rem % nk;
        int rem2 = rem / nk;
        int p    = rem2 & 1;
        int g    = (rem2 >> 1) & 3;
        int jt   = rem2 >> 3;
        int r15  = lane & 15, kq = lane >> 4;
        int row  = g * hd + jt * 16 + r15;

        bf16x8 o8;
        #pragma unroll
        for (int e = 0; e < 8; ++e) {
            int k = kt * 32 + kq * 8 + e;
            float v = 0.0f;
            if (k < xw) v = wih[(size_t)row * wihld + k];
            else if (k >= din && k < Kp) v = whh[(size_t)row * whhld + (k - din)];
            __bf16 h = (__bf16)v;
            o8[e] = p ? (__bf16)(v - (float)h) : h;
        }
        *(bf16x8*)(dst0 + g_woff[l] + (size_t)di * 8) = o8;
    }
}

__device__ __forceinline__ void unpack8(const uint4& a, const uint4& b, bf16x8& bh, bf16x8& bl) {
    union { u32 u[4]; bf16x8 v; } H, L;
    H.u[0] = (a.x & 0xFFFFu) | (a.y << 16);
    H.u[1] = (a.z & 0xFFFFu) | (a.w << 16);
    H.u[2] = (b.x & 0xFFFFu) | (b.y << 16);
    H.u[3] = (b.z & 0xFFFFu) | (b.w << 16);
    L.u[0] = (a.x >> 16) | (a.y & 0xFFFF0000u);
    L.u[1] = (a.z >> 16) | (a.w & 0xFFFF0000u);
    L.u[2] = (b.x >> 16) | (b.y & 0xFFFF0000u);
    L.u[3] = (b.z >> 16) | (b.w & 0xFFFF0000u);
    bh = H.v; bl = L.v;
}

/* Persistent kernel, round-5 structure with XCD-clustered mapping.
   Grid 256 (16 idle), 512 thr = 8 waves x 16 batches.
   bid%8 = XCD (heuristic; correctness placement-agnostic):
     xcd 0-4 : layer xcd,   32 blocks (16 jt x 2 bt)
     xcd 5   : layers 5,6   (8 jt x 2 bt each)
     xcd 6   : layers 7,8
     xcd 7   : layer 9 (16 blocks; slots 16-31 idle)                    */
__global__ __launch_bounds__(512, 2) void lstm_persist(
    const float* __restrict__ b_1, const float* __restrict__ b_2,
    u32* __restrict__ wsd, float* __restrict__ out)
{
    __shared__ __align__(16) u16 A_sh[65536];   /* 128 KiB */

    const int bid = blockIdx.x;
    const int xcd = bid & 7, slot = bid >> 3;
    int l, jt, bt;
    if (xcd < 5)      { l = xcd;               bt = slot >> 4;        jt = slot & 15; }
    else if (xcd == 5){ l = 5 + (slot >> 4);   bt = (slot >> 3) & 1;  jt = slot & 7; }
    else if (xcd == 6){ l = 7 + (slot >> 4);   bt = (slot >> 3) & 1;  jt = slot & 7; }
    else              { if (slot >= 16) return; l = 9; bt = slot >> 3; jt = slot & 7; }

    const int hd  = (l < 5) ? 256 : 128;
    const int din = (l == 0) ? 32 : ((l < 6) ? 256 : 128);
    const int nk  = (din + hd) >> 5;
    const float* bias = (l < 5) ? (b_1 + l * 1024) : (b_2 + (l - 5) * 512);

    u32* hbuf = wsd;
    u32* ctr  = wsd + CTR_OFF;
    const u32* xp = wsd + XP_OFF;
    const u16* wt = (const u16*)(wsd + WT_OFF);

    const int tid  = threadIdx.x;
    const int lane = tid & 63;
    const int wv   = tid >> 6;
    const int r15  = lane & 15;
    const int kq   = lane >> 4;
    const int brow = bt * 128 + wv * 16 + r15;
    const int j0   = jt * 16 + kq * 4;

    /* one-time: copy this block's fragment-ordered weight slice into LDS */
    {
        const uint4* src = (const uint4*)(wt + g_woff[l] + (size_t)jt * 8 * nk * 512);
        uint4* dst = (uint4*)A_sh;
        const int n4 = nk * 512;
        for (int i = tid; i < n4; i += 512) dst[i] = src[i];
    }
    __syncthreads();

    float bgr[4][4];
    #pragma unroll
    for (int g = 0; g < 4; ++g) {
        float4 v = *(const float4*)&bias[g * hd + j0];
        bgr[g][0] = v.x; bgr[g][1] = v.y; bgr[g][2] = v.z; bgr[g][3] = v.w;
    }

    int offH[4], offL[4];
    #pragma unroll
    for (int g = 0; g < 4; ++g) {
        offH[g] = (g * 2)     * nk * 512 + lane * 8;
        offL[g] = (g * 2 + 1) * nk * 512 + lane * 8;
    }

    float4 cv = make_float4(0.f, 0.f, 0.f, 0.f);
    const int lm = (l > 0) ? (l - 1) : 0;

    for (int w = 0; w < NSTEPS; ++w) {
        const int t = w - l;
        if (t >= 0 && t < TT) {
            const u32* hin   = hbuf + ((size_t)lm * 2 + (t & 1)) * (BB * HD);
            const u32* hprev = hbuf + ((size_t)l * 2 + ((t & 1) ^ 1)) * (BB * HD);
            u32*       hout  = hbuf + ((size_t)l * 2 + (t & 1)) * (BB * HD);

            auto loadB = [&](int kt, uint4& A, uint4& B) {
                if (l == 0) {
                    if (kt == 0) {
                        if (kq == 0) {
                            const uint4* p = (const uint4*)(xp + ((size_t)brow * TT + t) * 8);
                            A = p[0]; B = p[1];
                        } else { A = make_uint4(0,0,0,0); B = make_uint4(0,0,0,0); }
                    } else {
                        const u32* p = hprev + (size_t)brow * HD + (kt * 32 - 32) + kq * 8;
                        A = *(const uint4*)p; B = *(const uint4*)(p + 4);
                    }
                } else {
                    int k0 = kt * 32 + kq * 8;
                    const u32* p = (k0 < din) ? (hin + (size_t)brow * HD + k0)
                                              : (hprev + (size_t)brow * HD + (k0 - din));
                    A = *(const uint4*)p; B = *(const uint4*)(p + 4);
                }
            };

            f32x4 acc0 = {0.f,0.f,0.f,0.f}, acc1 = {0.f,0.f,0.f,0.f};
            f32x4 acc2 = {0.f,0.f,0.f,0.f}, acc3 = {0.f,0.f,0.f,0.f};

            uint4 cA, cB, nA, nB;
            loadB(0, cA, cB);
            if (nk > 1) loadB(1, nA, nB);

            for (int kt = 0; kt < nk; ++kt) {
                uint4 fA, fB;
                if (kt + 2 < nk) loadB(kt + 2, fA, fB);

                bf16x8 bh, bl;
                unpack8(cA, cB, bh, bl);

                const int kof = kt * 512;
                bf16x8 a0h = *(const bf16x8*)&A_sh[offH[0] + kof];
                bf16x8 a1h = *(const bf16x8*)&A_sh[offH[1] + kof];
                bf16x8 a2h = *(const bf16x8*)&A_sh[offH[2] + kof];
                bf16x8 a3h = *(const bf16x8*)&A_sh[offH[3] + kof];
                bf16x8 a0l = *(const bf16x8*)&A_sh[offL[0] + kof];
                bf16x8 a1l = *(const bf16x8*)&A_sh[offL[1] + kof];
                bf16x8 a2l = *(const bf16x8*)&A_sh[offL[2] + kof];
                bf16x8 a3l = *(const bf16x8*)&A_sh[offL[3] + kof];

                acc0 = __builtin_amdgcn_mfma_f32_16x16x32_bf16(a0h, bh, acc0, 0, 0, 0);
                acc1 = __builtin_amdgcn_mfma_f32_16x16x32_bf16(a1h, bh, acc1, 0, 0, 0);
                acc2 = __builtin_amdgcn_mfma_f32_16x16x32_bf16(a2h, bh, acc2, 0, 0, 0);
                acc3 = __builtin_amdgcn_mfma_f32_16x16x32_bf16(a3h, bh, acc3, 0, 0, 0);
                acc0 = __builtin_amdgcn_mfma_f32_16x16x32_bf16(a0h, bl, acc0, 0, 0, 0);
                acc1 = __builtin_amdgcn_mfma_f32_16x16x32_bf16(a1h, bl, acc1, 0, 0, 0);
                acc2 = __builtin_amdgcn_mfma_f32_16x16x32_bf16(a2h, bl, acc2, 0, 0, 0);
                acc3 = __builtin_amdgcn_mfma_f32_16x16x32_bf16(a3h, bl, acc3, 0, 0, 0);
                acc0 = __builtin_amdgcn_mfma_f32_16x16x32_bf16(a0l, bh, acc0, 0, 0, 0);
                acc1 = __builtin_amdgcn_mfma_f32_16x16x32_bf16(a1l, bh, acc1, 0, 0, 0);
                acc2 = __builtin_amdgcn_mfma_f32_16x16x32_bf16(a2l, bh, acc2, 0, 0, 0);
                acc3 = __builtin_amdgcn_mfma_f32_16x16x32_bf16(a3l, bh, acc3, 0, 0, 0);

                cA = nA; cB = nB; nA = fA; nB = fB;
            }

            /* epilogue: bias + activations + register c update */
            float4 hv;
            {
                float i_, f_, g_, o_;
                i_ = sigmoidf_(acc0[0] + bgr[0][0]); f_ = sigmoidf_(acc1[0] + bgr[1][0]);
                g_ = tanhf   (acc2[0] + bgr[2][0]); o_ = sigmoidf_(acc3[0] + bgr[3][0]);
                cv.x = fmaf(f_, cv.x, i_ * g_); hv.x = o_ * tanhf(cv.x);
                i_ = sigmoidf_(acc0[1] + bgr[0][1]); f_ = sigmoidf_(acc1[1] + bgr[1][1]);
                g_ = tanhf   (acc2[1] + bgr[2][1]); o_ = sigmoidf_(acc3[1] + bgr[3][1]);
                cv.y = fmaf(f_, cv.y, i_ * g_); hv.y = o_ * tanhf(cv.y);
                i_ = sigmoidf_(acc0[2] + bgr[0][2]); f_ = sigmoidf_(acc1[2] + bgr[1][2]);
                g_ = tanhf   (acc2[2] + bgr[2][2]); o_ = sigmoidf_(acc3[2] + bgr[3][2]);
                cv.z = fmaf(f_, cv.z, i_ * g_); hv.z = o_ * tanhf(cv.z);
                i_ = sigmoidf_(acc0[3] + bgr[0][3]); f_ = sigmoidf_(acc1[3] + bgr[1][3]);
                g_ = tanhf   (acc2[3] + bgr[2][3]); o_ = sigmoidf_(acc3[3] + bgr[3][3]);
                cv.w = fmaf(f_, cv.w, i_ * g_); hv.w = o_ * tanhf(cv.w);
            }

            /* pack h -> u32 (hi|lo<<16); write-through agent atomic stores */
            u32 pk0, pk1, pk2, pk3;
            {
                u16 h0 = f2bf_hi(hv.x); pk0 = (u32)h0 | ((u32)f2bf_hi(hv.x - bf2f(h0)) << 16);
                u16 h1 = f2bf_hi(hv.y); pk1 = (u32)h1 | ((u32)f2bf_hi(hv.y - bf2f(h1)) << 16);
                u16 h2 = f2bf_hi(hv.z); pk2 = (u32)h2 | ((u32)f2bf_hi(hv.z - bf2f(h2)) << 16);
                u16 h3 = f2bf_hi(hv.w); pk3 = (u32)h3 | ((u32)f2bf_hi(hv.w - bf2f(h3)) << 16);
            }
            u64* hp = (u64*)(hout + (size_t)brow * HD + j0);
            __hip_atomic_store(hp + 0, (u64)pk0 | ((u64)pk1 << 32), __ATOMIC_RELAXED, __HIP_MEMORY_SCOPE_AGENT);
            __hip_atomic_store(hp + 1, (u64)pk2 | ((u64)pk3 << 32), __ATOMIC_RELAXED, __HIP_MEMORY_SCOPE_AGENT);

            if (l == 9 && t == TT - 1)
                *(float4*)&out[(size_t)brow * ED + j0] = hv;
        }

        /* ---- global barrier (r5 proven): syncthreads drains stores; tid0
           arrives at its XCD counter, polls all 8, then acquire-inv ---- */
        __syncthreads();
        if (tid == 0) {
            __hip_atomic_fetch_add(&ctr[xcd * 32], 1u,
                                   __ATOMIC_RELAXED, __HIP_MEMORY_SCOPE_AGENT);
            const u32 w1 = (u32)(w + 1);
            for (int it = 0; it < (1 << 22); ++it) {
                bool ok = true;
                #pragma unroll
                for (int r = 0; r < 8; ++r) {
                    u32 tgt = ((r == 7) ? 16u : 32u) * w1;
                    ok &= (__hip_atomic_load(&ctr[r * 32], __ATOMIC_RELAXED,
                                             __HIP_MEMORY_SCOPE_AGENT) >= tgt);
                }
                if (ok) break;
                __builtin_amdgcn_s_sleep(2);
            }
            __builtin_amdgcn_fence(__ATOMIC_ACQUIRE, "agent");  /* inv, no writeback */
        }
        __syncthreads();
    }
}

extern "C" void kernel_launch(void* const* d_in, const int* in_sizes, int n_in,
                              void* d_out, int out_size, void* d_ws, size_t ws_size,
                              hipStream_t stream) {
    const float* x       = (const float*)d_in[0];
    const float* w_ih0_1 = (const float*)d_in[1];
    const float* w_ihr_1 = (const float*)d_in[2];
    const float* w_hh_1  = (const float*)d_in[3];
    const float* b_1     = (const float*)d_in[4];
    const float* w_ih0_2 = (const float*)d_in[5];
    const float* w_ihr_2 = (const float*)d_in[6];
    const float* w_hh_2  = (const float*)d_in[7];
    const float* b_2     = (const float*)d_in[8];
    u32*   wsd = (u32*)d_ws;
    float* out = (float*)d_out;

    hipLaunchKernelGGL(zero_state, dim3(1024), dim3(256), 0, stream, wsd);
    hipLaunchKernelGGL(conv_all, dim3(1024), dim3(256), 0, stream,
                       w_ih0_1, w_ihr_1, w_hh_1, w_ih0_2, w_ihr_2, w_hh_2, wsd);
    hipLaunchKernelGGL(conv_x, dim3(256), dim3(256), 0, stream, x, wsd);
    hipLaunchKernelGGL(lstm_persist, dim3(256), dim3(512), 0, stream,
                       b_1, b_2, wsd, out);
}

// Round 10
// 3285.925 us; speedup vs baseline: 3.2697x; 1.0267x over previous
//
#include <hip/hip_runtime.h>
#include <math.h>

typedef unsigned short u16;
typedef unsigned int   u32;
typedef unsigned long long u64;
typedef __bf16 bf16x8 __attribute__((ext_vector_type(8)));
typedef float  f32x4  __attribute__((ext_vector_type(4)));

#define BB 256
#define TT 256
#define HD 256
#define ED 128
#define NSTEPS 265

/* ws layout (u32 units):
   [0, H_U32)        : h ping-pong, packed bf16 hi|lo<<16  [10][2][256][256]
   [CTR_OFF, +512)   : 8 barrier counters (128B padded) + gen broadcast @+256
   [XP_OFF, +XP_U32) : packed x  [256][256][8]
   [WT_OFF, ...)     : fragment-ordered bf16 weights (r4-r9 proven layout) */
#define H_U32   (10 * 2 * BB * HD)
#define CTR_OFF H_U32
#define CTR_U32 512
#define XP_OFF  (H_U32 + CTR_U32)
#define XP_U32  (BB * TT * 8)
#define WT_OFF  (XP_OFF + XP_U32)

__constant__ size_t g_woff[10] = {0ul,589824ul,1638400ul,2686976ul,3735552ul,
                                  4784128ul,5177344ul,5439488ul,5701632ul,5963776ul};
__constant__ int g_cb[11] = {0,73728,204800,335872,466944,598016,
                             647168,679936,712704,745472,778240};

__device__ __forceinline__ u16 f2bf_hi(float f) {
    u32 u = __float_as_uint(f);
    u32 r = (u + 0x7FFFu + ((u >> 16) & 1u)) >> 16;
    return (u16)r;
}
__device__ __forceinline__ float bf2f(u16 h) { return __uint_as_float(((u32)h) << 16); }
__device__ __forceinline__ float sigmoidf_(float v) { return 1.0f / (1.0f + expf(-v)); }

__global__ __launch_bounds__(256) void zero_state(u32* wsd) {
    const int n = XP_OFF;
    for (int i = blockIdx.x * blockDim.x + threadIdx.x; i < n; i += gridDim.x * blockDim.x)
        wsd[i] = 0u;
}

__global__ __launch_bounds__(256) void conv_x(const float* __restrict__ x, u32* __restrict__ wsd) {
    u32* xp = wsd + XP_OFF;
    for (int i = blockIdx.x * blockDim.x + threadIdx.x; i < XP_U32; i += gridDim.x * blockDim.x) {
        float v = x[i];
        u16 hi = f2bf_hi(v);
        u16 lo = f2bf_hi(v - bf2f(hi));
        xp[i] = (u32)hi | ((u32)lo << 16);
    }
}

/* weights -> bf16 hi/lo, MFMA fragment order (identical to rounds 4-9) */
__global__ __launch_bounds__(256) void conv_all(
    const float* __restrict__ w_ih0_1, const float* __restrict__ w_ihr_1,
    const float* __restrict__ w_hh_1,
    const float* __restrict__ w_ih0_2, const float* __restrict__ w_ihr_2,
    const float* __restrict__ w_hh_2,
    u32* __restrict__ wsd)
{
    __bf16* dst0 = (__bf16*)(wsd + WT_OFF);
    const int nch = 778240;
    for (int ci = blockIdx.x * blockDim.x + threadIdx.x; ci < nch;
         ci += gridDim.x * blockDim.x) {
        int l = 0;
        while (ci >= g_cb[l + 1]) ++l;
        int di = ci - g_cb[l];

        const int hd  = (l < 5) ? 256 : 128;
        const int din = (l == 0) ? 32 : ((l < 6) ? 256 : 128);
        const int xw  = (l == 0) ? 8 : din;
        const int Kp  = din + hd;
        const int nk  = Kp >> 5;

        const float *wih, *whh; int wihld, whhld;
        if (l == 0)      { wih = w_ih0_1;                                whh = w_hh_1;
                           wihld = 8;   whhld = 256; }
        else if (l < 5)  { wih = w_ihr_1 + (size_t)(l - 1) * 1024 * 256; whh = w_hh_1 + (size_t)l * 1024 * 256;
                           wihld = 256; whhld = 256; }
        else if (l == 5) { wih = w_ih0_2;                                whh = w_hh_2;
                           wihld = 256; whhld = 128; }
        else             { wih = w_ihr_2 + (size_t)(l - 6) * 512 * 128;  whh = w_hh_2 + (size_t)(l - 5) * 512 * 128;
                           wihld = 128; whhld = 128; }

        int lane = di & 63;
        int rem  = di >> 6;
        int kt   = rem % nk;
        int rem2 = rem / nk;
        int p    = rem2 & 1;
        int g    = (rem2 >> 1) & 3;
        int jt   = rem2 >> 3;
        int r15  = lane & 15, kq = lane >> 4;
        int row  = g * hd + jt * 16 + r15;

        bf16x8 o8;
        #pragma unroll
        for (int e = 0; e < 8; ++e) {
            int k = kt * 32 + kq * 8 + e;
            float v = 0.0f;
            if (k < xw) v = wih[(size_t)row * wihld + k];
            else if (k >= din && k < Kp) v = whh[(size_t)row * whhld + (k - din)];
            __bf16 h = (__bf16)v;
            o8[e] = p ? (__bf16)(v - (float)h) : h;
        }
        *(bf16x8*)(dst0 + g_woff[l] + (size_t)di * 8) = o8;
    }
}

__device__ __forceinline__ void unpack8(const uint4& a, const uint4& b, bf16x8& bh, bf16x8& bl) {
    union { u32 u[4]; bf16x8 v; } H, L;
    H.u[0] = (a.x & 0xFFFFu) | (a.y << 16);
    H.u[1] = (a.z & 0xFFFFu) | (a.w << 16);
    H.u[2] = (b.x & 0xFFFFu) | (b.y << 16);
    H.u[3] = (b.z & 0xFFFFu) | (b.w << 16);
    L.u[0] = (a.x >> 16) | (a.y & 0xFFFF0000u);
    L.u[1] = (a.z >> 16) | (a.w & 0xFFFF0000u);
    L.u[2] = (b.x >> 16) | (b.y & 0xFFFF0000u);
    L.u[3] = (b.z >> 16) | (b.w & 0xFFFF0000u);
    bh = H.v; bl = L.v;
}

/* persistent step loop, compile-time K structure; ring-8 B prefetch */
template<int NKI, int NKT, bool ISL0>
__device__ void run_persist(int l, int bid, int xcd, int jt, int bt, int hd,
    const float* __restrict__ bias, u32* __restrict__ hbuf, u32* __restrict__ ctr,
    const u32* __restrict__ xp, float* __restrict__ out, const u16* __restrict__ A_sh)
{
    constexpr int DIN = NKI * 32;
    constexpr int RD  = (NKT < 8) ? NKT : 8;

    const int tid  = threadIdx.x;
    const int lane = tid & 63;
    const int wv   = tid >> 6;
    const int r15  = lane & 15;
    const int kq   = lane >> 4;
    const int brow = bt * 128 + wv * 16 + r15;
    const int j0   = jt * 16 + kq * 4;

    float bgr[4][4];
    #pragma unroll
    for (int g = 0; g < 4; ++g) {
        float4 v = *(const float4*)&bias[g * hd + j0];
        bgr[g][0] = v.x; bgr[g][1] = v.y; bgr[g][2] = v.z; bgr[g][3] = v.w;
    }

    int offH[4], offL[4];
    #pragma unroll
    for (int g = 0; g < 4; ++g) {
        offH[g] = (g * 2)     * NKT * 512 + lane * 8;
        offL[g] = (g * 2 + 1) * NKT * 512 + lane * 8;
    }

    float4 cv = make_float4(0.f, 0.f, 0.f, 0.f);
    const int lm = (l > 0) ? (l - 1) : 0;

    for (int w = 0; w < NSTEPS; ++w) {
        const int t = w - l;
        if (t >= 0 && t < TT) {
            const u32* hin   = hbuf + ((size_t)lm * 2 + (t & 1)) * (BB * HD);
            const u32* hprev = hbuf + ((size_t)l * 2 + ((t & 1) ^ 1)) * (BB * HD);
            u32*       hout  = hbuf + ((size_t)l * 2 + (t & 1)) * (BB * HD);

            auto ldB = [&](int kt, uint4& A, uint4& B) {
                if constexpr (ISL0) {
                    if (kt == 0) {
                        if (kq == 0) {
                            const uint4* p = (const uint4*)(xp + ((size_t)brow * TT + t) * 8);
                            A = p[0]; B = p[1];
                        } else { A = make_uint4(0,0,0,0); B = make_uint4(0,0,0,0); }
                    } else {
                        const u32* p = hprev + (size_t)brow * HD + (kt * 32 - 32) + kq * 8;
                        A = *(const uint4*)p; B = *(const uint4*)(p + 4);
                    }
                } else {
                    const int k0 = kt * 32 + kq * 8;
                    const u32* p = (kt < NKI) ? (hin + (size_t)brow * HD + k0)
                                              : (hprev + (size_t)brow * HD + (k0 - DIN));
                    A = *(const uint4*)p; B = *(const uint4*)(p + 4);
                }
            };

            f32x4 acc0 = {0.f,0.f,0.f,0.f}, acc1 = {0.f,0.f,0.f,0.f};
            f32x4 acc2 = {0.f,0.f,0.f,0.f}, acc3 = {0.f,0.f,0.f,0.f};

            uint4 rA[RD], rB[RD];
            #pragma unroll
            for (int i = 0; i < RD; ++i) ldB(i, rA[i], rB[i]);

            #pragma unroll
            for (int kt = 0; kt < NKT; ++kt) {
                bf16x8 bh, bl;
                unpack8(rA[kt % RD], rB[kt % RD], bh, bl);
                if (kt + RD < NKT) ldB(kt + RD, rA[kt % RD], rB[kt % RD]);

                const int kof = kt * 512;
                bf16x8 a0h = *(const bf16x8*)&A_sh[offH[0] + kof];
                bf16x8 a1h = *(const bf16x8*)&A_sh[offH[1] + kof];
                bf16x8 a2h = *(const bf16x8*)&A_sh[offH[2] + kof];
                bf16x8 a3h = *(const bf16x8*)&A_sh[offH[3] + kof];
                bf16x8 a0l = *(const bf16x8*)&A_sh[offL[0] + kof];
                bf16x8 a1l = *(const bf16x8*)&A_sh[offL[1] + kof];
                bf16x8 a2l = *(const bf16x8*)&A_sh[offL[2] + kof];
                bf16x8 a3l = *(const bf16x8*)&A_sh[offL[3] + kof];

                acc0 = __builtin_amdgcn_mfma_f32_16x16x32_bf16(a0h, bh, acc0, 0, 0, 0);
                acc1 = __builtin_amdgcn_mfma_f32_16x16x32_bf16(a1h, bh, acc1, 0, 0, 0);
                acc2 = __builtin_amdgcn_mfma_f32_16x16x32_bf16(a2h, bh, acc2, 0, 0, 0);
                acc3 = __builtin_amdgcn_mfma_f32_16x16x32_bf16(a3h, bh, acc3, 0, 0, 0);
                acc0 = __builtin_amdgcn_mfma_f32_16x16x32_bf16(a0h, bl, acc0, 0, 0, 0);
                acc1 = __builtin_amdgcn_mfma_f32_16x16x32_bf16(a1h, bl, acc1, 0, 0, 0);
                acc2 = __builtin_amdgcn_mfma_f32_16x16x32_bf16(a2h, bl, acc2, 0, 0, 0);
                acc3 = __builtin_amdgcn_mfma_f32_16x16x32_bf16(a3h, bl, acc3, 0, 0, 0);
                acc0 = __builtin_amdgcn_mfma_f32_16x16x32_bf16(a0l, bh, acc0, 0, 0, 0);
                acc1 = __builtin_amdgcn_mfma_f32_16x16x32_bf16(a1l, bh, acc1, 0, 0, 0);
                acc2 = __builtin_amdgcn_mfma_f32_16x16x32_bf16(a2l, bh, acc2, 0, 0, 0);
                acc3 = __builtin_amdgcn_mfma_f32_16x16x32_bf16(a3l, bh, acc3, 0, 0, 0);
            }

            /* epilogue: bias + activations + register c update */
            float4 hv;
            {
                float i_, f_, g_, o_;
                i_ = sigmoidf_(acc0[0] + bgr[0][0]); f_ = sigmoidf_(acc1[0] + bgr[1][0]);
                g_ = tanhf   (acc2[0] + bgr[2][0]); o_ = sigmoidf_(acc3[0] + bgr[3][0]);
                cv.x = fmaf(f_, cv.x, i_ * g_); hv.x = o_ * tanhf(cv.x);
                i_ = sigmoidf_(acc0[1] + bgr[0][1]); f_ = sigmoidf_(acc1[1] + bgr[1][1]);
                g_ = tanhf   (acc2[1] + bgr[2][1]); o_ = sigmoidf_(acc3[1] + bgr[3][1]);
                cv.y = fmaf(f_, cv.y, i_ * g_); hv.y = o_ * tanhf(cv.y);
                i_ = sigmoidf_(acc0[2] + bgr[0][2]); f_ = sigmoidf_(acc1[2] + bgr[1][2]);
                g_ = tanhf   (acc2[2] + bgr[2][2]); o_ = sigmoidf_(acc3[2] + bgr[3][2]);
                cv.z = fmaf(f_, cv.z, i_ * g_); hv.z = o_ * tanhf(cv.z);
                i_ = sigmoidf_(acc0[3] + bgr[0][3]); f_ = sigmoidf_(acc1[3] + bgr[1][3]);
                g_ = tanhf   (acc2[3] + bgr[2][3]); o_ = sigmoidf_(acc3[3] + bgr[3][3]);
                cv.w = fmaf(f_, cv.w, i_ * g_); hv.w = o_ * tanhf(cv.w);
            }

            /* pack h -> u32 (hi|lo<<16); write-through agent atomic stores */
            u32 pk0, pk1, pk2, pk3;
            {
                u16 h0 = f2bf_hi(hv.x); pk0 = (u32)h0 | ((u32)f2bf_hi(hv.x - bf2f(h0)) << 16);
                u16 h1 = f2bf_hi(hv.y); pk1 = (u32)h1 | ((u32)f2bf_hi(hv.y - bf2f(h1)) << 16);
                u16 h2 = f2bf_hi(hv.z); pk2 = (u32)h2 | ((u32)f2bf_hi(hv.z - bf2f(h2)) << 16);
                u16 h3 = f2bf_hi(hv.w); pk3 = (u32)h3 | ((u32)f2bf_hi(hv.w - bf2f(h3)) << 16);
            }
            u64* hp = (u64*)(hout + (size_t)brow * HD + j0);
            __hip_atomic_store(hp + 0, (u64)pk0 | ((u64)pk1 << 32), __ATOMIC_RELAXED, __HIP_MEMORY_SCOPE_AGENT);
            __hip_atomic_store(hp + 1, (u64)pk2 | ((u64)pk3 << 32), __ATOMIC_RELAXED, __HIP_MEMORY_SCOPE_AGENT);

            if (l == 9 && t == TT - 1)
                *(float4*)&out[(size_t)brow * ED + j0] = hv;
        }

        /* ---- global barrier: arrivals per-XCD; block 0 aggregates and
           broadcasts a generation word; everyone polls one word ---- */
        __syncthreads();
        if (tid == 0) {
            __hip_atomic_fetch_add(&ctr[xcd * 32], 1u,
                                   __ATOMIC_RELAXED, __HIP_MEMORY_SCOPE_AGENT);
            const u32 w1 = (u32)(w + 1);
            if (bid == 0) {
                for (int it = 0; it < (1 << 22); ++it) {
                    bool ok = true;
                    #pragma unroll
                    for (int r = 0; r < 8; ++r) {
                        u32 tgt = ((r == 7) ? 16u : 32u) * w1;
                        ok &= (__hip_atomic_load(&ctr[r * 32], __ATOMIC_RELAXED,
                                                 __HIP_MEMORY_SCOPE_AGENT) >= tgt);
                    }
                    if (ok) break;
                    __builtin_amdgcn_s_sleep(1);
                }
                __hip_atomic_store(&ctr[256], w1, __ATOMIC_RELAXED, __HIP_MEMORY_SCOPE_AGENT);
            } else {
                for (int it = 0; it < (1 << 22); ++it) {
                    if (__hip_atomic_load(&ctr[256], __ATOMIC_RELAXED,
                                          __HIP_MEMORY_SCOPE_AGENT) >= w1) break;
                    __builtin_amdgcn_s_sleep(1);
                }
            }
            __builtin_amdgcn_fence(__ATOMIC_ACQUIRE, "agent");  /* inv, no writeback */
        }
        __syncthreads();
    }
}

/* Grid 256 (16 idle), 512 thr = 8 waves x 16 batches.
   bid%8 = XCD heuristic (correctness placement-agnostic):
     xcd 0-4 : layer = xcd   (16 jt x 2 bt)
     xcd 5   : layers 5,6 ; xcd 6 : layers 7,8 ; xcd 7 : layer 9 (16 blk) */
__global__ __launch_bounds__(512, 2) void lstm_persist(
    const float* __restrict__ b_1, const float* __restrict__ b_2,
    u32* __restrict__ wsd, float* __restrict__ out)
{
    __shared__ __align__(16) u16 A_sh[65536];   /* 128 KiB */

    const int bid = blockIdx.x;
    const int xcd = bid & 7, slot = bid >> 3;
    int l, jt, bt;
    if (xcd < 5)      { l = xcd;               bt = slot >> 4;        jt = slot & 15; }
    else if (xcd == 5){ l = 5 + (slot >> 4);   bt = (slot >> 3) & 1;  jt = slot & 7; }
    else if (xcd == 6){ l = 7 + (slot >> 4);   bt = (slot >> 3) & 1;  jt = slot & 7; }
    else              { if (slot >= 16) return; l = 9; bt = slot >> 3; jt = slot & 7; }

    const int hd  = (l < 5) ? 256 : 128;
    const int din = (l == 0) ? 32 : ((l < 6) ? 256 : 128);
    const int nk  = (din + hd) >> 5;
    const float* bias = (l < 5) ? (b_1 + l * 1024) : (b_2 + (l - 5) * 512);

    u32* hbuf = wsd;
    u32* ctr  = wsd + CTR_OFF;
    const u32* xp = wsd + XP_OFF;
    const u16* wt = (const u16*)(wsd + WT_OFF);

    /* one-time: copy this block's fragment-ordered weight slice into LDS */
    {
        const uint4* src = (const uint4*)(wt + g_woff[l] + (size_t)jt * 8 * nk * 512);
        uint4* dst = (uint4*)A_sh;
        const int n4 = nk * 512;
        for (int i = threadIdx.x; i < n4; i += 512) dst[i] = src[i];
    }
    __syncthreads();

    if (l == 0)
        run_persist<1, 9, true >(l, bid, xcd, jt, bt, hd, bias, hbuf, ctr, xp, out, A_sh);
    else if (l < 5)
        run_persist<8, 16, false>(l, bid, xcd, jt, bt, hd, bias, hbuf, ctr, xp, out, A_sh);
    else if (l == 5)
        run_persist<8, 12, false>(l, bid, xcd, jt, bt, hd, bias, hbuf, ctr, xp, out, A_sh);
    else
        run_persist<4, 8, false>(l, bid, xcd, jt, bt, hd, bias, hbuf, ctr, xp, out, A_sh);
}

extern "C" void kernel_launch(void* const* d_in, const int* in_sizes, int n_in,
                              void* d_out, int out_size, void* d_ws, size_t ws_size,
                              hipStream_t stream) {
    const float* x       = (const float*)d_in[0];
    const float* w_ih0_1 = (const float*)d_in[1];
    const float* w_ihr_1 = (const float*)d_in[2];
    const float* w_hh_1  = (const float*)d_in[3];
    const float* b_1     = (const float*)d_in[4];
    const float* w_ih0_2 = (const float*)d_in[5];
    const float* w_ihr_2 = (const float*)d_in[6];
    const float* w_hh_2  = (const float*)d_in[7];
    const float* b_2     = (const float*)d_in[8];
    u32*   wsd = (u32*)d_ws;
    float* out = (float*)d_out;

    hipLaunchKernelGGL(zero_state, dim3(1024), dim3(256), 0, stream, wsd);
    hipLaunchKernelGGL(conv_all, dim3(1024), dim3(256), 0, stream,
                       w_ih0_1, w_ihr_1, w_hh_1, w_ih0_2, w_ihr_2, w_hh_2, wsd);
    hipLaunchKernelGGL(conv_x, dim3(256), dim3(256), 0, stream, x, wsd);
    hipLaunchKernelGGL(lstm_persist, dim3(256), dim3(512), 0, stream,
                       b_1, b_2, wsd, out);
}